// Round 22
// baseline (449.207 us; speedup 1.0000x reference)
//
#include <hip/hip_runtime.h>
#include <hip/hip_bf16.h>
#include <stdint.h>

// Problem constants (B=4, S=2048, H=1024, E=8, K=2)
#define E_    8
#define H_    1024
#define NTOK  8192           // B*S
#define KSEL  2
#define NSLOT (NTOK * KSEL)  // 16384

typedef __attribute__((ext_vector_type(8))) short   short8_t;  // 8 bf16 in 4 VGPRs
typedef __attribute__((ext_vector_type(4))) float   f32x4;

// GEMM tiling (R17/R19-verified optimum of 21 structural variants):
// 160x128, BK=64, 4 waves (2x2, per-wave 80x64), reg-staged bf16,
// XOR-swizzled LDS (36.9KB -> 4 blocks/CU, conflicts=0), raw lgkm-only
// barriers, NWG=880. + T5 setprio A/B this round (4 blocks/CU = wave
// role-diversity, the m218b precondition m190's null structure lacked).
#define BM 160
#define BN 128
#define BK 64
#define MAXMT 110
#define NT    (H_ / BN)      // 8 N-tiles
#define NWG   (MAXMT * NT)   // 880, div by 8 (bijective XCD swizzle)

// ---- workspace layout (bytes) ----
#define CNT_OFF   0
#define TOK_OFF   1024                     // NSLOT ints
#define WSL_OFF   (TOK_OFF + NSLOT * 4)    // NSLOT floats
#define XB_OFF    (1 << 18)                              // bf16 x (16.8 MB)
#define H1_OFF    (XB_OFF + (size_t)NTOK * H_ * 2)
#define W1T_OFF   (H1_OFF + (size_t)(NSLOT + 2048) * H_ * 2)
#define W2T_OFF   (W1T_OFF + (size_t)E_ * H_ * H_ * 2)

// ---------------------------------------------------------------------------
// Single-block deterministic router (R19-verified: no global atomics).
#define RT_T 1024
#define RT_S (NSLOT / RT_T)   // 16 slots per thread

__global__ __launch_bounds__(RT_T) void route_all(
    const int* __restrict__ idx, const float* __restrict__ tkw,
    int* __restrict__ cnt, int* __restrict__ tok, float* __restrict__ wsl) {
  __shared__ int hist[E_ * RT_T];   // 32 KB
  const int t = threadIdx.x;
  const int p0 = t * RT_S;

  int myi[RT_S];
#pragma unroll
  for (int i = 0; i < RT_S; i += 4)
    *(int4*)&myi[i] = *(const int4*)&idx[p0 + i];
  int lc[E_];
#pragma unroll
  for (int j = 0; j < E_; ++j) lc[j] = 0;
#pragma unroll
  for (int i = 0; i < RT_S; ++i)
#pragma unroll
    for (int j = 0; j < E_; ++j) lc[j] += (myi[i] == j) ? 1 : 0;

#pragma unroll
  for (int j = 0; j < E_; ++j) hist[j * RT_T + t] = lc[j];
  __syncthreads();

  for (int s = 1; s < RT_T; s <<= 1) {
    int v[E_];
#pragma unroll
    for (int j = 0; j < E_; ++j) v[j] = (t >= s) ? hist[j * RT_T + (t - s)] : 0;
    __syncthreads();
#pragma unroll
    for (int j = 0; j < E_; ++j) hist[j * RT_T + t] += v[j];
    __syncthreads();
  }

  int tot[E_];
#pragma unroll
  for (int j = 0; j < E_; ++j) tot[j] = hist[j * RT_T + (RT_T - 1)];
  int base[E_];
  {
    int s = 0;
#pragma unroll
    for (int j = 0; j < E_; ++j) { base[j] = s; s += tot[j]; }
  }
  if (t < E_) cnt[t] = tot[t];

  int cur[E_];
#pragma unroll
  for (int j = 0; j < E_; ++j) cur[j] = base[j] + hist[j * RT_T + t] - lc[j];

  float myw[RT_S];
#pragma unroll
  for (int i = 0; i < RT_S; i += 4)
    *(float4*)&myw[i] = *(const float4*)&tkw[p0 + i];
#pragma unroll
  for (int i = 0; i < RT_S; ++i) {
    const int ev = myi[i];
    int pos = 0;
#pragma unroll
    for (int j = 0; j < E_; ++j)
      if (ev == j) { pos = cur[j]; cur[j] = pos + 1; }
    tok[pos] = (p0 + i) >> 1;
    wsl[pos] = myw[i];
  }
}

// ---------------------------------------------------------------------------
// xb = (bf16) x  +  out zero.  16 elems/thread, 2048 blocks (R19-verified).
__global__ void xcast_zero(const float* __restrict__ x, __hip_bfloat16* __restrict__ xb,
                           float* __restrict__ out) {
  const size_t base = ((size_t)blockIdx.x * 256 + threadIdx.x) * 16;
  f32x4 z = f32x4{0.f, 0.f, 0.f, 0.f};
#pragma unroll
  for (int j = 0; j < 4; ++j) *(f32x4*)(out + base + j * 4) = z;
#pragma unroll
  for (int h = 0; h < 2; ++h) {
    f32x4 v0 = *(const f32x4*)(x + base + h * 8);
    f32x4 v1 = *(const f32x4*)(x + base + h * 8 + 4);
    union { __hip_bfloat16 b[8]; uint2 u[2]; } cv;
#pragma unroll
    for (int j = 0; j < 4; ++j) {
      cv.b[j]     = __float2bfloat16(v0[j]);
      cv.b[4 + j] = __float2bfloat16(v1[j]);
    }
    *(uint2*)(xb + base + h * 8)     = cv.u[0];
    *(uint2*)(xb + base + h * 8 + 4) = cv.u[1];
  }
}

// ---------------------------------------------------------------------------
// wt[e][f][h] = (bf16) w[e][h][f].  64x64 tiles, 256 threads (R13-verified).
__global__ void transpose_cast(const float* __restrict__ w1, const float* __restrict__ w2,
                               __hip_bfloat16* __restrict__ wt1, __hip_bfloat16* __restrict__ wt2) {
  __shared__ __hip_bfloat16 t[64][65];
  const int z = blockIdx.z;
  const float* W = (z < E_ ? w1 : w2) + ((size_t)(z & 7) << 20);
  __hip_bfloat16* WT = (z < E_ ? wt1 : wt2) + ((size_t)(z & 7) << 20);
  const int h0 = blockIdx.y * 64, f0 = blockIdx.x * 64;
  const int tid = threadIdx.x;
  const int tx = tid & 63, ty = tid >> 6;
#pragma unroll
  for (int i = 0; i < 16; ++i) {
    const int hl = i * 4 + ty;
    t[hl][tx] = __float2bfloat16(W[(size_t)(h0 + hl) * H_ + f0 + tx]);
  }
  __syncthreads();
  const int htx = tid & 15;
  const int fy  = tid >> 4;
#pragma unroll
  for (int j = 0; j < 4; ++j) {
    const int f = j * 16 + fy;
    union { __hip_bfloat16 h[4]; uint2 u; } v;
#pragma unroll
    for (int k = 0; k < 4; ++k) v.h[k] = t[htx * 4 + k][f];
    *reinterpret_cast<uint2*>(&WT[(size_t)(f0 + f) * H_ + h0 + htx * 4]) = v.u;
  }
}

// ---------------------------------------------------------------------------
// Grouped GEMM, single-buffer reg-staged, raw-barrier loop (R17/R19 verified):
//   { loadreg(kt+1) ; compute(kt) } -> lgkm0+bar -> dswrite(kt+1) -> lgkm0+bar
//   EPI=0: A = xb rows gathered via tok;  h1 = relu(AW^T+b)
//   EPI=1: A = h1 rows (linear);          out[tok[p]] += wsl[p]*(AW^T+b)
#define FENCE_BAR() do {                                   \
    asm volatile("s_waitcnt lgkmcnt(0)" ::: "memory");     \
    __builtin_amdgcn_s_barrier();                          \
    __builtin_amdgcn_sched_barrier(0);                     \
  } while (0)

template <int EPI>
__launch_bounds__(256, 4)
__global__ void moe_gemm(const __hip_bfloat16* __restrict__ Asrc,  // xb (EPI=0) / h1 (EPI=1)
                         const __hip_bfloat16* __restrict__ Wt,    // [E][H][H] (f-major)
                         const float* __restrict__ bias,           // [E][H]
                         __hip_bfloat16* __restrict__ h1out,
                         float* __restrict__ out,
                         const int* __restrict__ cnt,
                         const int* __restrict__ tok, const float* __restrict__ wsl) {
  // T1: bijective XCD swizzle (NWG % 8 == 0)
  const int wgid = (blockIdx.x & 7) * (NWG / 8) + (blockIdx.x >> 3);
  const int bt = wgid >> 3;
  const int nt = wgid & 7;

  // inline per-expert tile prefix from cnt[8] (R14-verified)
  int cn[E_];
#pragma unroll
  for (int i = 0; i < E_; ++i) cn[i] = cnt[i];
  int e = -1, mt = 0, count = 0, arow0 = 0;
  {
    int tacc = 0, sacc = 0;
#pragma unroll
    for (int i = 0; i < E_; ++i) {
      const int nti = (cn[i] + BM - 1) / BM;
      if (e < 0 && bt < tacc + nti) { e = i; mt = bt - tacc; count = cn[i]; arow0 = sacc + mt * BM; }
      tacc += nti; sacc += cn[i];
    }
  }
  if (e < 0) return;
  const size_t Arow0 = (size_t)arow0;

  const int tid = threadIdx.x;
  const int lane = tid & 63;
  const int wid = tid >> 6;
  const int wm = wid >> 1, wn = wid & 1;      // 2x2 waves; per-wave 80x64
  const int l15 = lane & 15, hi = lane >> 4, l7 = lane & 7;

  const __hip_bfloat16* Bexp = Wt + ((size_t)e << 20) + (size_t)(nt * BN) * H_;

  __shared__ __hip_bfloat16 smA[BM * BK];  // 20.0 KB
  __shared__ __hip_bfloat16 smB[BN * BK];  // 36.9 KB total -> 4 blocks/CU

  const int srow = tid >> 3;         // 0..31
  const int sun  = (tid & 7) * 8;    // linear global source offset (coalesced)
  const int swu  = (((tid & 7) ^ (srow & 7)) * 8);   // XOR-swizzled LDS unit

  const __hip_bfloat16* aptr[5];
#pragma unroll
  for (int i = 0; i < 5; ++i) {
    if constexpr (EPI == 0) {
      int p = arow0 + i * 32 + srow;
      if (p > NSLOT - 1) p = NSLOT - 1;
      aptr[i] = Asrc + (size_t)tok[p] * H_ + sun;
    } else {
      aptr[i] = Asrc + (Arow0 + i * 32 + srow) * H_ + sun;   // h1 has +2048-row slack
    }
  }
  const __hip_bfloat16* bptr = Bexp + (size_t)srow * H_ + sun;

  short8_t ra[5], rb[4];

  auto loadreg = [&](int kt) {
#pragma unroll
    for (int i = 0; i < 5; ++i)
      ra[i] = *(const short8_t*)(aptr[i] + kt * BK);
#pragma unroll
    for (int i = 0; i < 4; ++i)
      rb[i] = *(const short8_t*)(bptr + (size_t)(i * 32) * H_ + kt * BK);
  };
  auto dswrite = [&]() {
#pragma unroll
    for (int i = 0; i < 5; ++i)
      *(short8_t*)&smA[(i * 32 + srow) * BK + swu] = ra[i];
#pragma unroll
    for (int i = 0; i < 4; ++i)
      *(short8_t*)&smB[(i * 32 + srow) * BK + swu] = rb[i];
  };

  f32x4 acc[5][4];
#pragma unroll
  for (int mi = 0; mi < 5; ++mi)
#pragma unroll
    for (int ni = 0; ni < 4; ++ni) acc[mi][ni] = f32x4{0.f, 0.f, 0.f, 0.f};

  // ds_read swizzle: logical unit (ks*4+hi) of row r at phys (ks*4+hi)^(r&7); r&7==l7
  const int pu[2] = { ((0 * 4 + hi) ^ l7) * 8, ((1 * 4 + hi) ^ l7) * 8 };

  auto compute = [&]() {
#pragma unroll
    for (int ks = 0; ks < 2; ++ks) {
      short8_t a[5], b[4];
#pragma unroll
      for (int mi = 0; mi < 5; ++mi)
        a[mi] = *(const short8_t*)&smA[(wm * 80 + mi * 16 + l15) * BK + pu[ks]];
#pragma unroll
      for (int ni = 0; ni < 4; ++ni)
        b[ni] = *(const short8_t*)&smB[(wn * 64 + ni * 16 + l15) * BK + pu[ks]];
      __builtin_amdgcn_s_setprio(1);     // T5: favor MFMA-issuing wave
#pragma unroll
      for (int mi = 0; mi < 5; ++mi)
#pragma unroll
        for (int ni = 0; ni < 4; ++ni)
          acc[mi][ni] = __builtin_amdgcn_mfma_f32_16x16x32_bf16(a[mi], b[ni], acc[mi][ni], 0, 0, 0);
      __builtin_amdgcn_s_setprio(0);
    }
  };

  const int KT = H_ / BK;  // 16

  loadreg(0);
  dswrite();
  FENCE_BAR();

  for (int kt = 0; kt < KT; ++kt) {
    if (kt + 1 < KT) loadreg(kt + 1);  // in flight through compute + barrier
    compute();
    if (kt + 1 < KT) {
      FENCE_BAR();                      // all waves done reading tile kt
      dswrite();                        // counted per-reg vmcnt waits only
      FENCE_BAR();                      // writes visible
    }
  }

  // ---- epilogue: per-(mi,r) hoisted bound check (R13-verified) ----
  const int colb = nt * BN + wn * 64;
  float bv[4];
#pragma unroll
  for (int ni = 0; ni < 4; ++ni) bv[ni] = bias[e * H_ + colb + ni * 16 + l15];

  if constexpr (EPI == 0) {
#pragma unroll
    for (int mi = 0; mi < 5; ++mi)
#pragma unroll
      for (int r = 0; r < 4; ++r) {
        const int lr = wm * 80 + mi * 16 + hi * 4 + r;
        if (mt * BM + lr < count) {
          __hip_bfloat16* rp = h1out + (Arow0 + lr) * H_ + colb;
#pragma unroll
          for (int ni = 0; ni < 4; ++ni) {
            float v = acc[mi][ni][r] + bv[ni];
            rp[ni * 16 + l15] = __float2bfloat16(fmaxf(v, 0.f));
          }
        }
      }
  } else {
#pragma unroll
    for (int mi = 0; mi < 5; ++mi)
#pragma unroll
      for (int r = 0; r < 4; ++r) {
        const int lr = wm * 80 + mi * 16 + hi * 4 + r;
        if (mt * BM + lr < count) {
          const int p = arow0 + lr;
          float* rp = out + (size_t)tok[p] * H_ + colb;
          const float w = wsl[p];
#pragma unroll
          for (int ni = 0; ni < 4; ++ni)
            atomicAdd(rp + ni * 16 + l15, (acc[mi][ni][r] + bv[ni]) * w);
        }
      }
  }
}

// ---------------------------------------------------------------------------
extern "C" void kernel_launch(void* const* d_in, const int* in_sizes, int n_in,
                              void* d_out, int out_size, void* d_ws, size_t ws_size,
                              hipStream_t stream) {
  const float* x   = (const float*)d_in[0];
  const int*   idx = (const int*)d_in[1];
  const float* tkw = (const float*)d_in[2];
  const float* w1  = (const float*)d_in[3];
  const float* b1  = (const float*)d_in[4];
  const float* w2  = (const float*)d_in[5];
  const float* b2  = (const float*)d_in[6];
  float* out = (float*)d_out;

  uint8_t* ws = (uint8_t*)d_ws;
  int*   cnt  = (int*)(ws + CNT_OFF);
  int*   tok  = (int*)(ws + TOK_OFF);
  float* wsl  = (float*)(ws + WSL_OFF);
  __hip_bfloat16* xb  = (__hip_bfloat16*)(ws + XB_OFF);
  __hip_bfloat16* h1  = (__hip_bfloat16*)(ws + H1_OFF);
  __hip_bfloat16* w1t = (__hip_bfloat16*)(ws + W1T_OFF);
  __hip_bfloat16* w2t = (__hip_bfloat16*)(ws + W2T_OFF);

  // node 1: weight transpose+cast
  transpose_cast<<<dim3(H_ / 64, H_ / 64, 2 * E_), 256, 0, stream>>>(w1, w2, w1t, w2t);
  // node 2: deterministic atomic-free routing
  route_all<<<1, RT_T, 0, stream>>>(idx, tkw, cnt, tok, wsl);
  // node 3: x cast + out zero
  xcast_zero<<<NTOK * H_ / (256 * 16), 256, 0, stream>>>(x, xb, out);
  // nodes 4-5: grouped GEMMs (R17/R19 structure + T5 setprio A/B)
  moe_gemm<0><<<NWG, 256, 0, stream>>>(xb, w1t, b1, h1, nullptr, cnt, tok, wsl);
  moe_gemm<1><<<NWG, 256, 0, stream>>>(h1, w2t, b2, nullptr, out, cnt, tok, wsl);
}

// Round 23
// 185.518 us; speedup vs baseline: 2.4214x; 2.4214x over previous
//
#include <hip/hip_runtime.h>
#include <hip/hip_bf16.h>
#include <stdint.h>

// Problem constants (B=4, S=2048, H=1024, E=8, K=2)
#define E_    8
#define H_    1024
#define NTOK  8192           // B*S
#define KSEL  2
#define NSLOT (NTOK * KSEL)  // 16384

typedef __attribute__((ext_vector_type(8))) short   short8_t;  // 8 bf16 in 4 VGPRs
typedef __attribute__((ext_vector_type(4))) float   f32x4;

// GEMM tiling (R17/R19-verified optimum of 22 structural variants):
// 160x128, BK=64, 4 waves (2x2, per-wave 80x64), reg-staged bf16,
// XOR-swizzled LDS (36.9KB -> 4 blocks/CU, conflicts=0), raw lgkm-only
// barriers, NWG=880. NO setprio (R22: setprio broke B-panel L2 residency,
// FETCH 33->336MB, GEMM 82->213us — definitively refuted here).
#define BM 160
#define BN 128
#define BK 64
#define MAXMT 110
#define NT    (H_ / BN)      // 8 N-tiles
#define NWG   (MAXMT * NT)   // 880, div by 8 (bijective XCD swizzle)

// ---- workspace layout (bytes) ----
#define CNT_OFF   0
#define TOK_OFF   1024                     // NSLOT ints
#define WSL_OFF   (TOK_OFF + NSLOT * 4)    // NSLOT floats
#define XB_OFF    (1 << 18)                              // bf16 x (16.8 MB)
#define H1_OFF    (XB_OFF + (size_t)NTOK * H_ * 2)
#define W1T_OFF   (H1_OFF + (size_t)(NSLOT + 2048) * H_ * 2)
#define W2T_OFF   (W1T_OFF + (size_t)E_ * H_ * H_ * 2)

// ---------------------------------------------------------------------------
// Single-block deterministic router (R19-verified: no global atomics).
#define RT_T 1024
#define RT_S (NSLOT / RT_T)   // 16 slots per thread

__global__ __launch_bounds__(RT_T) void route_all(
    const int* __restrict__ idx, const float* __restrict__ tkw,
    int* __restrict__ cnt, int* __restrict__ tok, float* __restrict__ wsl) {
  __shared__ int hist[E_ * RT_T];   // 32 KB
  const int t = threadIdx.x;
  const int p0 = t * RT_S;

  int myi[RT_S];
#pragma unroll
  for (int i = 0; i < RT_S; i += 4)
    *(int4*)&myi[i] = *(const int4*)&idx[p0 + i];
  int lc[E_];
#pragma unroll
  for (int j = 0; j < E_; ++j) lc[j] = 0;
#pragma unroll
  for (int i = 0; i < RT_S; ++i)
#pragma unroll
    for (int j = 0; j < E_; ++j) lc[j] += (myi[i] == j) ? 1 : 0;

#pragma unroll
  for (int j = 0; j < E_; ++j) hist[j * RT_T + t] = lc[j];
  __syncthreads();

  for (int s = 1; s < RT_T; s <<= 1) {
    int v[E_];
#pragma unroll
    for (int j = 0; j < E_; ++j) v[j] = (t >= s) ? hist[j * RT_T + (t - s)] : 0;
    __syncthreads();
#pragma unroll
    for (int j = 0; j < E_; ++j) hist[j * RT_T + t] += v[j];
    __syncthreads();
  }

  int tot[E_];
#pragma unroll
  for (int j = 0; j < E_; ++j) tot[j] = hist[j * RT_T + (RT_T - 1)];
  int base[E_];
  {
    int s = 0;
#pragma unroll
    for (int j = 0; j < E_; ++j) { base[j] = s; s += tot[j]; }
  }
  if (t < E_) cnt[t] = tot[t];

  int cur[E_];
#pragma unroll
  for (int j = 0; j < E_; ++j) cur[j] = base[j] + hist[j * RT_T + t] - lc[j];

  float myw[RT_S];
#pragma unroll
  for (int i = 0; i < RT_S; i += 4)
    *(float4*)&myw[i] = *(const float4*)&tkw[p0 + i];
#pragma unroll
  for (int i = 0; i < RT_S; ++i) {
    const int ev = myi[i];
    int pos = 0;
#pragma unroll
    for (int j = 0; j < E_; ++j)
      if (ev == j) { pos = cur[j]; cur[j] = pos + 1; }
    tok[pos] = (p0 + i) >> 1;
    wsl[pos] = myw[i];
  }
}

// ---------------------------------------------------------------------------
// xb = (bf16) x  +  out zero.  16 elems/thread, 2048 blocks (R19-verified).
__global__ void xcast_zero(const float* __restrict__ x, __hip_bfloat16* __restrict__ xb,
                           float* __restrict__ out) {
  const size_t base = ((size_t)blockIdx.x * 256 + threadIdx.x) * 16;
  f32x4 z = f32x4{0.f, 0.f, 0.f, 0.f};
#pragma unroll
  for (int j = 0; j < 4; ++j) *(f32x4*)(out + base + j * 4) = z;
#pragma unroll
  for (int h = 0; h < 2; ++h) {
    f32x4 v0 = *(const f32x4*)(x + base + h * 8);
    f32x4 v1 = *(const f32x4*)(x + base + h * 8 + 4);
    union { __hip_bfloat16 b[8]; uint2 u[2]; } cv;
#pragma unroll
    for (int j = 0; j < 4; ++j) {
      cv.b[j]     = __float2bfloat16(v0[j]);
      cv.b[4 + j] = __float2bfloat16(v1[j]);
    }
    *(uint2*)(xb + base + h * 8)     = cv.u[0];
    *(uint2*)(xb + base + h * 8 + 4) = cv.u[1];
  }
}

// ---------------------------------------------------------------------------
// wt[e][f][h] = (bf16) w[e][h][f].  64x64 tiles, 256 threads (R13-verified).
__global__ void transpose_cast(const float* __restrict__ w1, const float* __restrict__ w2,
                               __hip_bfloat16* __restrict__ wt1, __hip_bfloat16* __restrict__ wt2) {
  __shared__ __hip_bfloat16 t[64][65];
  const int z = blockIdx.z;
  const float* W = (z < E_ ? w1 : w2) + ((size_t)(z & 7) << 20);
  __hip_bfloat16* WT = (z < E_ ? wt1 : wt2) + ((size_t)(z & 7) << 20);
  const int h0 = blockIdx.y * 64, f0 = blockIdx.x * 64;
  const int tid = threadIdx.x;
  const int tx = tid & 63, ty = tid >> 6;
#pragma unroll
  for (int i = 0; i < 16; ++i) {
    const int hl = i * 4 + ty;
    t[hl][tx] = __float2bfloat16(W[(size_t)(h0 + hl) * H_ + f0 + tx]);
  }
  __syncthreads();
  const int htx = tid & 15;
  const int fy  = tid >> 4;
#pragma unroll
  for (int j = 0; j < 4; ++j) {
    const int f = j * 16 + fy;
    union { __hip_bfloat16 h[4]; uint2 u; } v;
#pragma unroll
    for (int k = 0; k < 4; ++k) v.h[k] = t[htx * 4 + k][f];
    *reinterpret_cast<uint2*>(&WT[(size_t)(f0 + f) * H_ + h0 + htx * 4]) = v.u;
  }
}

// ---------------------------------------------------------------------------
// Grouped GEMM, single-buffer reg-staged, raw-barrier loop (R17/R19 verified):
//   { loadreg(kt+1) ; compute(kt) } -> lgkm0+bar -> dswrite(kt+1) -> lgkm0+bar
//   EPI=0: A = xb rows gathered via tok;  h1 = relu(AW^T+b)
//   EPI=1: A = h1 rows (linear);          out[tok[p]] += wsl[p]*(AW^T+b)
#define FENCE_BAR() do {                                   \
    asm volatile("s_waitcnt lgkmcnt(0)" ::: "memory");     \
    __builtin_amdgcn_s_barrier();                          \
    __builtin_amdgcn_sched_barrier(0);                     \
  } while (0)

template <int EPI>
__launch_bounds__(256, 4)
__global__ void moe_gemm(const __hip_bfloat16* __restrict__ Asrc,  // xb (EPI=0) / h1 (EPI=1)
                         const __hip_bfloat16* __restrict__ Wt,    // [E][H][H] (f-major)
                         const float* __restrict__ bias,           // [E][H]
                         __hip_bfloat16* __restrict__ h1out,
                         float* __restrict__ out,
                         const int* __restrict__ cnt,
                         const int* __restrict__ tok, const float* __restrict__ wsl) {
  // T1: bijective XCD swizzle (NWG % 8 == 0)
  const int wgid = (blockIdx.x & 7) * (NWG / 8) + (blockIdx.x >> 3);
  const int bt = wgid >> 3;
  const int nt = wgid & 7;

  // inline per-expert tile prefix from cnt[8] (R14-verified)
  int cn[E_];
#pragma unroll
  for (int i = 0; i < E_; ++i) cn[i] = cnt[i];
  int e = -1, mt = 0, count = 0, arow0 = 0;
  {
    int tacc = 0, sacc = 0;
#pragma unroll
    for (int i = 0; i < E_; ++i) {
      const int nti = (cn[i] + BM - 1) / BM;
      if (e < 0 && bt < tacc + nti) { e = i; mt = bt - tacc; count = cn[i]; arow0 = sacc + mt * BM; }
      tacc += nti; sacc += cn[i];
    }
  }
  if (e < 0) return;
  const size_t Arow0 = (size_t)arow0;

  const int tid = threadIdx.x;
  const int lane = tid & 63;
  const int wid = tid >> 6;
  const int wm = wid >> 1, wn = wid & 1;      // 2x2 waves; per-wave 80x64
  const int l15 = lane & 15, hi = lane >> 4, l7 = lane & 7;

  const __hip_bfloat16* Bexp = Wt + ((size_t)e << 20) + (size_t)(nt * BN) * H_;

  __shared__ __hip_bfloat16 smA[BM * BK];  // 20.0 KB
  __shared__ __hip_bfloat16 smB[BN * BK];  // 36.9 KB total -> 4 blocks/CU

  const int srow = tid >> 3;         // 0..31
  const int sun  = (tid & 7) * 8;    // linear global source offset (coalesced)
  const int swu  = (((tid & 7) ^ (srow & 7)) * 8);   // XOR-swizzled LDS unit

  const __hip_bfloat16* aptr[5];
#pragma unroll
  for (int i = 0; i < 5; ++i) {
    if constexpr (EPI == 0) {
      int p = arow0 + i * 32 + srow;
      if (p > NSLOT - 1) p = NSLOT - 1;
      aptr[i] = Asrc + (size_t)tok[p] * H_ + sun;
    } else {
      aptr[i] = Asrc + (Arow0 + i * 32 + srow) * H_ + sun;   // h1 has +2048-row slack
    }
  }
  const __hip_bfloat16* bptr = Bexp + (size_t)srow * H_ + sun;

  short8_t ra[5], rb[4];

  auto loadreg = [&](int kt) {
#pragma unroll
    for (int i = 0; i < 5; ++i)
      ra[i] = *(const short8_t*)(aptr[i] + kt * BK);
#pragma unroll
    for (int i = 0; i < 4; ++i)
      rb[i] = *(const short8_t*)(bptr + (size_t)(i * 32) * H_ + kt * BK);
  };
  auto dswrite = [&]() {
#pragma unroll
    for (int i = 0; i < 5; ++i)
      *(short8_t*)&smA[(i * 32 + srow) * BK + swu] = ra[i];
#pragma unroll
    for (int i = 0; i < 4; ++i)
      *(short8_t*)&smB[(i * 32 + srow) * BK + swu] = rb[i];
  };

  f32x4 acc[5][4];
#pragma unroll
  for (int mi = 0; mi < 5; ++mi)
#pragma unroll
    for (int ni = 0; ni < 4; ++ni) acc[mi][ni] = f32x4{0.f, 0.f, 0.f, 0.f};

  // ds_read swizzle: logical unit (ks*4+hi) of row r at phys (ks*4+hi)^(r&7); r&7==l7
  const int pu[2] = { ((0 * 4 + hi) ^ l7) * 8, ((1 * 4 + hi) ^ l7) * 8 };

  auto compute = [&]() {
#pragma unroll
    for (int ks = 0; ks < 2; ++ks) {
      short8_t a[5], b[4];
#pragma unroll
      for (int mi = 0; mi < 5; ++mi)
        a[mi] = *(const short8_t*)&smA[(wm * 80 + mi * 16 + l15) * BK + pu[ks]];
#pragma unroll
      for (int ni = 0; ni < 4; ++ni)
        b[ni] = *(const short8_t*)&smB[(wn * 64 + ni * 16 + l15) * BK + pu[ks]];
#pragma unroll
      for (int mi = 0; mi < 5; ++mi)
#pragma unroll
        for (int ni = 0; ni < 4; ++ni)
          acc[mi][ni] = __builtin_amdgcn_mfma_f32_16x16x32_bf16(a[mi], b[ni], acc[mi][ni], 0, 0, 0);
    }
  };

  const int KT = H_ / BK;  // 16

  loadreg(0);
  dswrite();
  FENCE_BAR();

  for (int kt = 0; kt < KT; ++kt) {
    if (kt + 1 < KT) loadreg(kt + 1);  // in flight through compute + barrier
    compute();
    if (kt + 1 < KT) {
      FENCE_BAR();                      // all waves done reading tile kt
      dswrite();                        // counted per-reg vmcnt waits only
      FENCE_BAR();                      // writes visible
    }
  }

  // ---- epilogue: per-(mi,r) hoisted bound check (R13-verified) ----
  const int colb = nt * BN + wn * 64;
  float bv[4];
#pragma unroll
  for (int ni = 0; ni < 4; ++ni) bv[ni] = bias[e * H_ + colb + ni * 16 + l15];

  if constexpr (EPI == 0) {
#pragma unroll
    for (int mi = 0; mi < 5; ++mi)
#pragma unroll
      for (int r = 0; r < 4; ++r) {
        const int lr = wm * 80 + mi * 16 + hi * 4 + r;
        if (mt * BM + lr < count) {
          __hip_bfloat16* rp = h1out + (Arow0 + lr) * H_ + colb;
#pragma unroll
          for (int ni = 0; ni < 4; ++ni) {
            float v = acc[mi][ni][r] + bv[ni];
            rp[ni * 16 + l15] = __float2bfloat16(fmaxf(v, 0.f));
          }
        }
      }
  } else {
#pragma unroll
    for (int mi = 0; mi < 5; ++mi)
#pragma unroll
      for (int r = 0; r < 4; ++r) {
        const int lr = wm * 80 + mi * 16 + hi * 4 + r;
        if (mt * BM + lr < count) {
          const int p = arow0 + lr;
          float* rp = out + (size_t)tok[p] * H_ + colb;
          const float w = wsl[p];
#pragma unroll
          for (int ni = 0; ni < 4; ++ni)
            atomicAdd(rp + ni * 16 + l15, (acc[mi][ni][r] + bv[ni]) * w);
        }
      }
  }
}

// ---------------------------------------------------------------------------
extern "C" void kernel_launch(void* const* d_in, const int* in_sizes, int n_in,
                              void* d_out, int out_size, void* d_ws, size_t ws_size,
                              hipStream_t stream) {
  const float* x   = (const float*)d_in[0];
  const int*   idx = (const int*)d_in[1];
  const float* tkw = (const float*)d_in[2];
  const float* w1  = (const float*)d_in[3];
  const float* b1  = (const float*)d_in[4];
  const float* w2  = (const float*)d_in[5];
  const float* b2  = (const float*)d_in[6];
  float* out = (float*)d_out;

  uint8_t* ws = (uint8_t*)d_ws;
  int*   cnt  = (int*)(ws + CNT_OFF);
  int*   tok  = (int*)(ws + TOK_OFF);
  float* wsl  = (float*)(ws + WSL_OFF);
  __hip_bfloat16* xb  = (__hip_bfloat16*)(ws + XB_OFF);
  __hip_bfloat16* h1  = (__hip_bfloat16*)(ws + H1_OFF);
  __hip_bfloat16* w1t = (__hip_bfloat16*)(ws + W1T_OFF);
  __hip_bfloat16* w2t = (__hip_bfloat16*)(ws + W2T_OFF);

  // node 1: weight transpose+cast
  transpose_cast<<<dim3(H_ / 64, H_ / 64, 2 * E_), 256, 0, stream>>>(w1, w2, w1t, w2t);
  // node 2: deterministic atomic-free routing
  route_all<<<1, RT_T, 0, stream>>>(idx, tkw, cnt, tok, wsl);
  // node 3: x cast + out zero
  xcast_zero<<<NTOK * H_ / (256 * 16), 256, 0, stream>>>(x, xb, out);
  // nodes 4-5: grouped GEMMs (R17/R19 structure, no setprio)
  moe_gemm<0><<<NWG, 256, 0, stream>>>(xb, w1t, b1, h1, nullptr, cnt, tok, wsl);
  moe_gemm<1><<<NWG, 256, 0, stream>>>(h1, w2t, b2, nullptr, out, cnt, tok, wsl);
}

// Round 24
// 182.242 us; speedup vs baseline: 2.4649x; 1.0180x over previous
//
#include <hip/hip_runtime.h>
#include <hip/hip_bf16.h>
#include <stdint.h>

// Problem constants (B=4, S=2048, H=1024, E=8, K=2)
#define E_    8
#define H_    1024
#define NTOK  8192           // B*S
#define KSEL  2
#define NSLOT (NTOK * KSEL)  // 16384

typedef __attribute__((ext_vector_type(8))) short   short8_t;  // 8 bf16 in 4 VGPRs
typedef __attribute__((ext_vector_type(4))) float   f32x4;

// GEMM tiling (R17/R19/R23-verified optimum of 23 structural variants):
// 160x128, BK=64, 4 waves (2x2, per-wave 80x64), reg-staged bf16,
// XOR-swizzled LDS (36.9KB -> 4 blocks/CU, conflicts=0), raw lgkm-only
// barriers, NWG=880. No setprio (R22: broke B-panel L2 residency, 2.6x).
#define BM 160
#define BN 128
#define BK 64
#define MAXMT 110
#define NT    (H_ / BN)      // 8 N-tiles
#define NWG   (MAXMT * NT)   // 880, div by 8 (bijective XCD swizzle)

// ---- workspace layout (bytes) ----
#define CNT_OFF   0
#define TOK_OFF   1024                     // NSLOT ints
#define WSL_OFF   (TOK_OFF + NSLOT * 4)    // NSLOT floats
#define XB_OFF    (1 << 18)                              // bf16 x (16.8 MB)
#define H1_OFF    (XB_OFF + (size_t)NTOK * H_ * 2)
#define W1T_OFF   (H1_OFF + (size_t)(NSLOT + 2048) * H_ * 2)
#define W2T_OFF   (W1T_OFF + (size_t)E_ * H_ * H_ * 2)

// ---------------------------------------------------------------------------
// Single-block deterministic router (R19-verified: no global atomics).
#define RT_T 1024
#define RT_S (NSLOT / RT_T)   // 16 slots per thread

__global__ __launch_bounds__(RT_T) void route_all(
    const int* __restrict__ idx, const float* __restrict__ tkw,
    int* __restrict__ cnt, int* __restrict__ tok, float* __restrict__ wsl) {
  __shared__ int hist[E_ * RT_T];   // 32 KB
  const int t = threadIdx.x;
  const int p0 = t * RT_S;

  int myi[RT_S];
#pragma unroll
  for (int i = 0; i < RT_S; i += 4)
    *(int4*)&myi[i] = *(const int4*)&idx[p0 + i];
  int lc[E_];
#pragma unroll
  for (int j = 0; j < E_; ++j) lc[j] = 0;
#pragma unroll
  for (int i = 0; i < RT_S; ++i)
#pragma unroll
    for (int j = 0; j < E_; ++j) lc[j] += (myi[i] == j) ? 1 : 0;

#pragma unroll
  for (int j = 0; j < E_; ++j) hist[j * RT_T + t] = lc[j];
  __syncthreads();

  for (int s = 1; s < RT_T; s <<= 1) {
    int v[E_];
#pragma unroll
    for (int j = 0; j < E_; ++j) v[j] = (t >= s) ? hist[j * RT_T + (t - s)] : 0;
    __syncthreads();
#pragma unroll
    for (int j = 0; j < E_; ++j) hist[j * RT_T + t] += v[j];
    __syncthreads();
  }

  int tot[E_];
#pragma unroll
  for (int j = 0; j < E_; ++j) tot[j] = hist[j * RT_T + (RT_T - 1)];
  int base[E_];
  {
    int s = 0;
#pragma unroll
    for (int j = 0; j < E_; ++j) { base[j] = s; s += tot[j]; }
  }
  if (t < E_) cnt[t] = tot[t];

  int cur[E_];
#pragma unroll
  for (int j = 0; j < E_; ++j) cur[j] = base[j] + hist[j * RT_T + t] - lc[j];

  float myw[RT_S];
#pragma unroll
  for (int i = 0; i < RT_S; i += 4)
    *(float4*)&myw[i] = *(const float4*)&tkw[p0 + i];
#pragma unroll
  for (int i = 0; i < RT_S; ++i) {
    const int ev = myi[i];
    int pos = 0;
#pragma unroll
    for (int j = 0; j < E_; ++j)
      if (ev == j) { pos = cur[j]; cur[j] = pos + 1; }
    tok[pos] = (p0 + i) >> 1;
    wsl[pos] = myw[i];
  }
}

// ---------------------------------------------------------------------------
// Fused prep: blocks [0,4096) = weight transpose+cast (16x16x16 grid flattened);
// blocks [4096,6144) = x cast + out zero. Both independent; one node.
__global__ void prep_fused(const float* __restrict__ w1, const float* __restrict__ w2,
                           __hip_bfloat16* __restrict__ wt1, __hip_bfloat16* __restrict__ wt2,
                           const float* __restrict__ x, __hip_bfloat16* __restrict__ xb,
                           float* __restrict__ out) {
  const int tid = threadIdx.x;
  if (blockIdx.x < 4096) {
    // ---- transpose_cast (R13-verified), flat-decoded block coords ----
    const int b  = blockIdx.x;
    const int z  = b >> 8;            // 0..15
    const int by = (b >> 4) & 15;
    const int bx = b & 15;
    __shared__ __hip_bfloat16 t[64][65];
    const float* W = (z < E_ ? w1 : w2) + ((size_t)(z & 7) << 20);
    __hip_bfloat16* WT = (z < E_ ? wt1 : wt2) + ((size_t)(z & 7) << 20);
    const int h0 = by * 64, f0 = bx * 64;
    const int tx = tid & 63, ty = tid >> 6;
#pragma unroll
    for (int i = 0; i < 16; ++i) {
      const int hl = i * 4 + ty;
      t[hl][tx] = __float2bfloat16(W[(size_t)(h0 + hl) * H_ + f0 + tx]);
    }
    __syncthreads();
    const int htx = tid & 15;
    const int fy  = tid >> 4;
#pragma unroll
    for (int j = 0; j < 4; ++j) {
      const int f = j * 16 + fy;
      union { __hip_bfloat16 h[4]; uint2 u; } v;
#pragma unroll
      for (int k = 0; k < 4; ++k) v.h[k] = t[htx * 4 + k][f];
      *reinterpret_cast<uint2*>(&WT[(size_t)(f0 + f) * H_ + h0 + htx * 4]) = v.u;
    }
  } else {
    // ---- xcast + out zero (R19-verified), 16 elems/thread ----
    const size_t base = ((size_t)(blockIdx.x - 4096) * 256 + tid) * 16;
    f32x4 z4 = f32x4{0.f, 0.f, 0.f, 0.f};
#pragma unroll
    for (int j = 0; j < 4; ++j) *(f32x4*)(out + base + j * 4) = z4;
#pragma unroll
    for (int h = 0; h < 2; ++h) {
      f32x4 v0 = *(const f32x4*)(x + base + h * 8);
      f32x4 v1 = *(const f32x4*)(x + base + h * 8 + 4);
      union { __hip_bfloat16 b[8]; uint2 u[2]; } cv;
#pragma unroll
      for (int j = 0; j < 4; ++j) {
        cv.b[j]     = __float2bfloat16(v0[j]);
        cv.b[4 + j] = __float2bfloat16(v1[j]);
      }
      *(uint2*)(xb + base + h * 8)     = cv.u[0];
      *(uint2*)(xb + base + h * 8 + 4) = cv.u[1];
    }
  }
}

// ---------------------------------------------------------------------------
// Grouped GEMM, single-buffer reg-staged, raw-barrier loop (R17/R19/R23):
//   { loadreg(kt+1) ; compute(kt) } -> lgkm0+bar -> dswrite(kt+1) -> lgkm0+bar
//   EPI=0: A = xb rows gathered via tok;  h1 = relu(AW^T+b)
//   EPI=1: A = h1 rows (linear);          out[tok[p]] += wsl[p]*(AW^T+b)
#define FENCE_BAR() do {                                   \
    asm volatile("s_waitcnt lgkmcnt(0)" ::: "memory");     \
    __builtin_amdgcn_s_barrier();                          \
    __builtin_amdgcn_sched_barrier(0);                     \
  } while (0)

template <int EPI>
__launch_bounds__(256, 4)
__global__ void moe_gemm(const __hip_bfloat16* __restrict__ Asrc,  // xb (EPI=0) / h1 (EPI=1)
                         const __hip_bfloat16* __restrict__ Wt,    // [E][H][H] (f-major)
                         const float* __restrict__ bias,           // [E][H]
                         __hip_bfloat16* __restrict__ h1out,
                         float* __restrict__ out,
                         const int* __restrict__ cnt,
                         const int* __restrict__ tok, const float* __restrict__ wsl) {
  // T1: bijective XCD swizzle (NWG % 8 == 0)
  const int wgid = (blockIdx.x & 7) * (NWG / 8) + (blockIdx.x >> 3);
  const int bt = wgid >> 3;
  const int nt = wgid & 7;

  // inline per-expert tile prefix from cnt[8] (R14-verified)
  int cn[E_];
#pragma unroll
  for (int i = 0; i < E_; ++i) cn[i] = cnt[i];
  int e = -1, mt = 0, count = 0, arow0 = 0;
  {
    int tacc = 0, sacc = 0;
#pragma unroll
    for (int i = 0; i < E_; ++i) {
      const int nti = (cn[i] + BM - 1) / BM;
      if (e < 0 && bt < tacc + nti) { e = i; mt = bt - tacc; count = cn[i]; arow0 = sacc + mt * BM; }
      tacc += nti; sacc += cn[i];
    }
  }
  if (e < 0) return;
  const size_t Arow0 = (size_t)arow0;

  const int tid = threadIdx.x;
  const int lane = tid & 63;
  const int wid = tid >> 6;
  const int wm = wid >> 1, wn = wid & 1;      // 2x2 waves; per-wave 80x64
  const int l15 = lane & 15, hi = lane >> 4, l7 = lane & 7;

  const __hip_bfloat16* Bexp = Wt + ((size_t)e << 20) + (size_t)(nt * BN) * H_;

  __shared__ __hip_bfloat16 smA[BM * BK];  // 20.0 KB
  __shared__ __hip_bfloat16 smB[BN * BK];  // 36.9 KB total -> 4 blocks/CU

  const int srow = tid >> 3;         // 0..31
  const int sun  = (tid & 7) * 8;    // linear global source offset (coalesced)
  const int swu  = (((tid & 7) ^ (srow & 7)) * 8);   // XOR-swizzled LDS unit

  const __hip_bfloat16* aptr[5];
#pragma unroll
  for (int i = 0; i < 5; ++i) {
    if constexpr (EPI == 0) {
      int p = arow0 + i * 32 + srow;
      if (p > NSLOT - 1) p = NSLOT - 1;
      aptr[i] = Asrc + (size_t)tok[p] * H_ + sun;
    } else {
      aptr[i] = Asrc + (Arow0 + i * 32 + srow) * H_ + sun;   // h1 has +2048-row slack
    }
  }
  const __hip_bfloat16* bptr = Bexp + (size_t)srow * H_ + sun;

  short8_t ra[5], rb[4];

  auto loadreg = [&](int kt) {
#pragma unroll
    for (int i = 0; i < 5; ++i)
      ra[i] = *(const short8_t*)(aptr[i] + kt * BK);
#pragma unroll
    for (int i = 0; i < 4; ++i)
      rb[i] = *(const short8_t*)(bptr + (size_t)(i * 32) * H_ + kt * BK);
  };
  auto dswrite = [&]() {
#pragma unroll
    for (int i = 0; i < 5; ++i)
      *(short8_t*)&smA[(i * 32 + srow) * BK + swu] = ra[i];
#pragma unroll
    for (int i = 0; i < 4; ++i)
      *(short8_t*)&smB[(i * 32 + srow) * BK + swu] = rb[i];
  };

  f32x4 acc[5][4];
#pragma unroll
  for (int mi = 0; mi < 5; ++mi)
#pragma unroll
    for (int ni = 0; ni < 4; ++ni) acc[mi][ni] = f32x4{0.f, 0.f, 0.f, 0.f};

  // ds_read swizzle: logical unit (ks*4+hi) of row r at phys (ks*4+hi)^(r&7); r&7==l7
  const int pu[2] = { ((0 * 4 + hi) ^ l7) * 8, ((1 * 4 + hi) ^ l7) * 8 };

  auto compute = [&]() {
#pragma unroll
    for (int ks = 0; ks < 2; ++ks) {
      short8_t a[5], b[4];
#pragma unroll
      for (int mi = 0; mi < 5; ++mi)
        a[mi] = *(const short8_t*)&smA[(wm * 80 + mi * 16 + l15) * BK + pu[ks]];
#pragma unroll
      for (int ni = 0; ni < 4; ++ni)
        b[ni] = *(const short8_t*)&smB[(wn * 64 + ni * 16 + l15) * BK + pu[ks]];
#pragma unroll
      for (int mi = 0; mi < 5; ++mi)
#pragma unroll
        for (int ni = 0; ni < 4; ++ni)
          acc[mi][ni] = __builtin_amdgcn_mfma_f32_16x16x32_bf16(a[mi], b[ni], acc[mi][ni], 0, 0, 0);
    }
  };

  const int KT = H_ / BK;  // 16

  loadreg(0);
  dswrite();
  FENCE_BAR();

  for (int kt = 0; kt < KT; ++kt) {
    if (kt + 1 < KT) loadreg(kt + 1);  // in flight through compute + barrier
    compute();
    if (kt + 1 < KT) {
      FENCE_BAR();                      // all waves done reading tile kt
      dswrite();                        // counted per-reg vmcnt waits only
      FENCE_BAR();                      // writes visible
    }
  }

  // ---- epilogue: per-(mi,r) hoisted bound check (R13-verified) ----
  const int colb = nt * BN + wn * 64;
  float bv[4];
#pragma unroll
  for (int ni = 0; ni < 4; ++ni) bv[ni] = bias[e * H_ + colb + ni * 16 + l15];

  if constexpr (EPI == 0) {
#pragma unroll
    for (int mi = 0; mi < 5; ++mi)
#pragma unroll
      for (int r = 0; r < 4; ++r) {
        const int lr = wm * 80 + mi * 16 + hi * 4 + r;
        if (mt * BM + lr < count) {
          __hip_bfloat16* rp = h1out + (Arow0 + lr) * H_ + colb;
#pragma unroll
          for (int ni = 0; ni < 4; ++ni) {
            float v = acc[mi][ni][r] + bv[ni];
            rp[ni * 16 + l15] = __float2bfloat16(fmaxf(v, 0.f));
          }
        }
      }
  } else {
#pragma unroll
    for (int mi = 0; mi < 5; ++mi)
#pragma unroll
      for (int r = 0; r < 4; ++r) {
        const int lr = wm * 80 + mi * 16 + hi * 4 + r;
        if (mt * BM + lr < count) {
          const int p = arow0 + lr;
          float* rp = out + (size_t)tok[p] * H_ + colb;
          const float w = wsl[p];
#pragma unroll
          for (int ni = 0; ni < 4; ++ni)
            atomicAdd(rp + ni * 16 + l15, (acc[mi][ni][r] + bv[ni]) * w);
        }
      }
  }
}

// ---------------------------------------------------------------------------
extern "C" void kernel_launch(void* const* d_in, const int* in_sizes, int n_in,
                              void* d_out, int out_size, void* d_ws, size_t ws_size,
                              hipStream_t stream) {
  const float* x   = (const float*)d_in[0];
  const int*   idx = (const int*)d_in[1];
  const float* tkw = (const float*)d_in[2];
  const float* w1  = (const float*)d_in[3];
  const float* b1  = (const float*)d_in[4];
  const float* w2  = (const float*)d_in[5];
  const float* b2  = (const float*)d_in[6];
  float* out = (float*)d_out;

  uint8_t* ws = (uint8_t*)d_ws;
  int*   cnt  = (int*)(ws + CNT_OFF);
  int*   tok  = (int*)(ws + TOK_OFF);
  float* wsl  = (float*)(ws + WSL_OFF);
  __hip_bfloat16* xb  = (__hip_bfloat16*)(ws + XB_OFF);
  __hip_bfloat16* h1  = (__hip_bfloat16*)(ws + H1_OFF);
  __hip_bfloat16* w1t = (__hip_bfloat16*)(ws + W1T_OFF);
  __hip_bfloat16* w2t = (__hip_bfloat16*)(ws + W2T_OFF);

  // node 1: fused prep — weight transpose+cast ∥ x cast ∥ out zero
  prep_fused<<<4096 + NTOK * H_ / (256 * 16), 256, 0, stream>>>(
      w1, w2, w1t, w2t, x, xb, out);
  // node 2: deterministic atomic-free routing
  route_all<<<1, RT_T, 0, stream>>>(idx, tkw, cnt, tok, wsl);
  // nodes 3-4: grouped GEMMs (R17/R19/R23 structure)
  moe_gemm<0><<<NWG, 256, 0, stream>>>(xb, w1t, b1, h1, nullptr, cnt, tok, wsl);
  moe_gemm<1><<<NWG, 256, 0, stream>>>(h1, w2t, b2, nullptr, out, cnt, tok, wsl);
}